// Round 4
// baseline (120.176 us; speedup 1.0000x reference)
//
#include <hip/hip_runtime.h>
#include <stdint.h>
#include <math.h>

#define D    2048
#define E    64
#define ROWS 16384
#define RB   256         // rows per block (lane owns 4 rows: lane + 64j)
#define BK   64          // k per chunk
#define EW   16          // experts per wave

typedef const __attribute__((address_space(1))) unsigned int guint;
typedef __attribute__((address_space(3))) unsigned int luint;

__device__ __forceinline__ void gl_lds16(const float* g, float* l) {
    __builtin_amdgcn_global_load_lds((guint*)g, (luint*)l, 16, 0, 0);
}

// ---------------- kernel 1: logits partials ----------------
// grid = 64 row-groups x NSPLIT k-splits, 256 threads (4 waves).
// Block covers 256 rows x 64 experts; wave w owns experts w*16..+15.
// Lane owns rows {lane+64j}. X: LDS (quad-swizzled, b128 per-lane reads).
// W: uniform-address VECTOR global loads (vz forces VGPR addressing),
//    pipelined by the compiler via vmcnt — no scalar-pipe stalls.
template<int NSPLIT>
__global__ __launch_bounds__(256, 1)
void logits_kernel(const float* __restrict__ x, const float* __restrict__ Wr,
                   float* __restrict__ P) {
    __shared__ float XS[2][RB * BK];   // 64 KB each, 128 KB total

    const int tid  = threadIdx.x;
    const int lane = tid & 63;
    const int wu   = __builtin_amdgcn_readfirstlane(tid >> 6);
    const int bid  = blockIdx.x;
    const int ks   = bid % NSPLIT;
    const int rg   = bid / NSPLIT;
    const int row0 = rg * RB;
    const int kb   = ks * (D / NSPLIT);
    const int NCH  = (D / NSPLIT) / BK;

    // forced-vector zero (opaque to compiler -> W addrs stay in VGPRs)
    int vz;
    asm volatile("v_mov_b32 %0, 0" : "=v"(vz));

    // staging: thread t, inst i: dest float off = i*1024 + t*4
    //   dest row r = i*16 + (t>>4); dest quad = t&15; src quad = (t&15)^(t>>4)
    const float* const xstage =
        x + (size_t)(row0 + (tid >> 4)) * D + kb + (((tid & 15) ^ (tid >> 4)) << 2);

#define STAGE(b, cc) do {                                                     \
        _Pragma("unroll")                                                     \
        for (int i = 0; i < 16; ++i)                                          \
            gl_lds16(xstage + (size_t)(cc) * BK + (size_t)i * 16 * D,         \
                     &XS[b][i * 1024 + tid * 4]);                             \
    } while (0)

    const int eb = wu * EW;
    // 16 hoisted W row bases (VGPR addrs); all (c,kq) offsets fold as imm
    const float* we[EW];
#pragma unroll
    for (int e = 0; e < EW; ++e)
        we[e] = Wr + (size_t)(eb + e) * D + kb + vz;

    float acc[4][EW];
#pragma unroll
    for (int j = 0; j < 4; ++j)
#pragma unroll
        for (int e = 0; e < EW; ++e) acc[j][e] = 0.0f;

    STAGE(0, 0);

    const int swq = (lane & 15) << 2;   // read-side quad swizzle (float units)
    int cur = 0;
    for (int c = 0; c < NCH; ++c) {
        asm volatile("s_waitcnt vmcnt(0)" ::: "memory");
        __syncthreads();
        if (c + 1 < NCH) STAGE(cur ^ 1, c + 1);

        const float* const xb = &XS[cur][0];
        int rowf[4];
#pragma unroll
        for (int j = 0; j < 4; ++j) rowf[j] = (64 * j + lane) * BK;

#pragma unroll
        for (int kq = 0; kq < 16; ++kq) {
            float4 xq[4];
#pragma unroll
            for (int j = 0; j < 4; ++j)
                xq[j] = *(const float4*)(xb + rowf[j] + (swq ^ (kq << 2)));
#pragma unroll
            for (int e = 0; e < EW; ++e) {
                const float4 wv = *(const float4*)(we[e] + c * BK + kq * 4);
#pragma unroll
                for (int j = 0; j < 4; ++j) {
                    acc[j][e] = fmaf(xq[j].x, wv.x, acc[j][e]);
                    acc[j][e] = fmaf(xq[j].y, wv.y, acc[j][e]);
                    acc[j][e] = fmaf(xq[j].z, wv.z, acc[j][e]);
                    acc[j][e] = fmaf(xq[j].w, wv.w, acc[j][e]);
                }
            }
        }
        cur ^= 1;
    }

    // partial store: P[ks][row][e]
#pragma unroll
    for (int j = 0; j < 4; ++j) {
        float* const pr = P + ((size_t)ks * ROWS + row0 + 64 * j + lane) * E + eb;
#pragma unroll
        for (int g = 0; g < 4; ++g)
            *(float4*)(pr + 4 * g) = make_float4(acc[j][4 * g + 0], acc[j][4 * g + 1],
                                                 acc[j][4 * g + 2], acc[j][4 * g + 3]);
    }
#undef STAGE
}

// ---------------- kernel 2: reduce + softmax + top-2 ----------------
template<int NSPLIT>
__global__ __launch_bounds__(256, 8)
void finish_kernel(const float* __restrict__ P, float* __restrict__ out) {
    const int lane = threadIdx.x & 63;
    const int w    = threadIdx.x >> 6;
    const int row  = blockIdx.x * 4 + w;

    float v = 0.0f;
#pragma unroll
    for (int s = 0; s < NSPLIT; ++s)
        v += P[((size_t)s * ROWS + row) * E + lane];

    float* const out_gw    = out;               // [16384][2]
    float* const out_idx   = out + 32768;       // [16384][2] (indices as floats)
    float* const out_probs = out + 65536;       // [16384][64]

    float m = v;
#pragma unroll
    for (int off = 32; off; off >>= 1) m = fmaxf(m, __shfl_xor(m, off));
    const float p = __expf(v - m);
    float s = p;
#pragma unroll
    for (int off = 32; off; off >>= 1) s += __shfl_xor(s, off);
    const float inv_s = 1.0f / s;

    out_probs[(size_t)row * 64 + lane] = p * inv_s;

    float v1 = v; int i1 = lane;
#pragma unroll
    for (int off = 32; off; off >>= 1) {
        const float ov = __shfl_xor(v1, off);
        const int   oi = __shfl_xor(i1, off);
        if (ov > v1 || (ov == v1 && oi < i1)) { v1 = ov; i1 = oi; }
    }
    float v2 = (lane == i1) ? -INFINITY : v; int i2 = lane;
#pragma unroll
    for (int off = 32; off; off >>= 1) {
        const float ov = __shfl_xor(v2, off);
        const int   oi = __shfl_xor(i2, off);
        if (ov > v2 || (ov == v2 && oi < i2)) { v2 = ov; i2 = oi; }
    }

    if (lane == 0) {
        const float p1 = __expf(v1 - m) * inv_s;
        const float p2 = __expf(v2 - m) * inv_s;
        const float inv12 = 1.0f / (p1 + p2);
        out_gw[(size_t)row * 2 + 0]  = p1 * inv12;
        out_gw[(size_t)row * 2 + 1]  = p2 * inv12;
        out_idx[(size_t)row * 2 + 0] = (float)i1;
        out_idx[(size_t)row * 2 + 1] = (float)i2;
    }
}

extern "C" void kernel_launch(void* const* d_in, const int* in_sizes, int n_in,
                              void* d_out, int out_size, void* d_ws, size_t ws_size,
                              hipStream_t stream) {
    const float* x  = (const float*)d_in[0];
    const float* Wr = (const float*)d_in[1];
    float* out = (float*)d_out;
    float* P   = (float*)d_ws;

    const size_t need4 = (size_t)4 * ROWS * E * sizeof(float);   // 16.8 MB
    if (ws_size >= need4) {
        hipLaunchKernelGGL((logits_kernel<4>), dim3((ROWS / RB) * 4), dim3(256), 0, stream, x, Wr, P);
        hipLaunchKernelGGL((finish_kernel<4>), dim3(ROWS / 4), dim3(256), 0, stream, P, out);
    } else {
        hipLaunchKernelGGL((logits_kernel<1>), dim3(ROWS / RB), dim3(256), 0, stream, x, Wr, P);
        hipLaunchKernelGGL((finish_kernel<1>), dim3(ROWS / 4), dim3(256), 0, stream, P, out);
    }
}